// Round 12
// baseline (152.292 us; speedup 1.0000x reference)
//
#include <hip/hip_runtime.h>

#define B   32
#define C   512
#define HID 32
#define HW  3136        // 56*56
#define HW4 784         // HW/4
#define POS 410         // round(0.8*512); threshold = sorted[POS-1]

typedef float f32x4 __attribute__((ext_vector_type(4)));

// ---------------------------------------------------------------------------
// D1: fused copy + per-channel mean (R10 pattern, best proven).
// 2048 blocks x 256 threads; each 32-lane group owns one channel.
// Plain loads + NT stores; no LDS/barriers in the hot loop.
// ---------------------------------------------------------------------------
__global__ __launch_bounds__(256) void copy_mean_kernel(const float* __restrict__ x,
                                                        float* __restrict__ out,
                                                        float* __restrict__ means) {
    const int t = threadIdx.x;
    const int k = t >> 5;                          // channel slot 0..7
    const int l = t & 31;                          // lane within group
    const size_t base = ((size_t)blockIdx.x * 8 + k) * HW4;   // float4 units
    const f32x4* xp = reinterpret_cast<const f32x4*>(x) + base;
    f32x4* op = reinterpret_cast<f32x4*>(out) + base;

    float s = 0.f;
    #pragma unroll 4
    for (int j = 0; j < 24; ++j) {                 // 24*32 = 768 float4
        f32x4 v = xp[j * 32 + l];
        __builtin_nontemporal_store(v, op + j * 32 + l);
        s += (v.x + v.y) + (v.z + v.w);
    }
    if (l < 16) {                                  // tail: 784 - 768 = 16
        f32x4 v = xp[768 + l];
        __builtin_nontemporal_store(v, op + 768 + l);
        s += (v.x + v.y) + (v.z + v.w);
    }

    #pragma unroll
    for (int off = 16; off > 0; off >>= 1)
        s += __shfl_xor(s, off, 32);
    if (l == 0)
        means[blockIdx.x * 8 + k] = s * (1.0f / HW);
}

// ---------------------------------------------------------------------------
// D2: redundant SE + zero-own-channels. 2048 blocks x 256 threads.
// Each block independently recomputes its batch's (b = bid>>6) excitation
// and rank threshold from means (identical fp sequence in all 64 blocks of
// a batch -> bit-identical thr, deterministic). Then zeroes its own 8
// channels (same ownership map as D1) where y > thr. No masks buffer,
// no atomics, no grid sync.
// ---------------------------------------------------------------------------
__global__ __launch_bounds__(256) void se_zero_kernel(const float* __restrict__ means,
                                                      const float* __restrict__ W1,
                                                      const float* __restrict__ W2,
                                                      float* __restrict__ out) {
    const int tid = threadIdx.x;
    const int b = blockIdx.x >> 6;                 // 64 blocks per batch
    __shared__ float m[C];
    __shared__ float y1[HID];
    __shared__ float y2[C];
    __shared__ float thr;

    m[tid]       = means[b * C + tid];
    m[tid + 256] = means[b * C + tid + 256];
    __syncthreads();

    {   // W1 dot: 8 lanes per hidden unit (h = tid>>3, l8 = tid&7)
        const int h = tid >> 3;
        const int l8 = tid & 7;
        const float* w = W1 + h * C;
        float acc = 0.f;
        for (int c = l8; c < C; c += 8) acc = fmaf(m[c], w[c], acc);
        #pragma unroll
        for (int off = 4; off > 0; off >>= 1) acc += __shfl_xor(acc, off, 8);
        if (l8 == 0) y1[h] = fmaxf(acc, 0.f);
    }
    __syncthreads();

    #pragma unroll
    for (int cc = tid; cc < C; cc += 256) {        // W2 dot + sigmoid
        const float* w = W2 + cc * HID;
        float acc = 0.f;
        #pragma unroll
        for (int h = 0; h < HID; ++h) acc = fmaf(y1[h], w[h], acc);
        y2[cc] = 1.f / (1.f + expf(-acc));
    }
    __syncthreads();

    #pragma unroll
    for (int cc = tid; cc < C; cc += 256) {        // rank w/ index tie-break
        const float v = y2[cc];
        int rank = 0;
        for (int j = 0; j < C; ++j) {
            float u = y2[j];
            rank += (u < v || (u == v && j < cc)) ? 1 : 0;
        }
        if (rank == POS - 1) thr = v;              // unique owner
    }
    __syncthreads();

    // zero my 8 channels where y > thr (mask==0)
    const int k = tid >> 5;
    const int l = tid & 31;
    const int ch = blockIdx.x * 8 + k;
    if (y2[ch & (C - 1)] > thr) {
        f32x4* op = reinterpret_cast<f32x4*>(out) + (size_t)ch * HW4;
        const f32x4 z = {0.f, 0.f, 0.f, 0.f};
        #pragma unroll 4
        for (int j = 0; j < 24; ++j)
            __builtin_nontemporal_store(z, op + j * 32 + l);
        if (l < 16)
            __builtin_nontemporal_store(z, op + 768 + l);
    }
}

extern "C" void kernel_launch(void* const* d_in, const int* in_sizes, int n_in,
                              void* d_out, int out_size, void* d_ws, size_t ws_size,
                              hipStream_t stream) {
    const float* x  = (const float*)d_in[0];
    const float* W1 = (const float*)d_in[1];
    const float* W2 = (const float*)d_in[2];
    float* out = (float*)d_out;
    float* means = (float*)d_ws;                   // B*C floats = 64 KB

    copy_mean_kernel<<<2048, 256, 0, stream>>>(x, out, means);
    se_zero_kernel<<<2048, 256, 0, stream>>>(means, W1, W2, out);
}

// Round 13
// 112.693 us; speedup vs baseline: 1.3514x; 1.3514x over previous
//
#include <hip/hip_runtime.h>

#define B   32
#define C   512
#define HID 32
#define HW  3136        // 56*56
#define HW4 784         // HW/4
#define POS 410         // round(0.8*512); threshold = sorted[POS-1]

typedef float f32x4 __attribute__((ext_vector_type(4)));

// ---------------------------------------------------------------------------
// D1: fused copy + per-channel mean (R10 pattern, best proven).
// 2048 blocks x 256 threads; each 32-lane group owns one channel.
// Plain loads + NT stores; no LDS/barriers in the hot loop.
// ---------------------------------------------------------------------------
__global__ __launch_bounds__(256) void copy_mean_kernel(const float* __restrict__ x,
                                                        float* __restrict__ out,
                                                        float* __restrict__ means) {
    const int t = threadIdx.x;
    const int k = t >> 5;                          // channel slot 0..7
    const int l = t & 31;                          // lane within group
    const size_t base = ((size_t)blockIdx.x * 8 + k) * HW4;   // float4 units
    const f32x4* xp = reinterpret_cast<const f32x4*>(x) + base;
    f32x4* op = reinterpret_cast<f32x4*>(out) + base;

    float s = 0.f;
    #pragma unroll 4
    for (int j = 0; j < 24; ++j) {                 // 24*32 = 768 float4
        f32x4 v = xp[j * 32 + l];
        __builtin_nontemporal_store(v, op + j * 32 + l);
        s += (v.x + v.y) + (v.z + v.w);
    }
    if (l < 16) {                                  // tail: 784 - 768 = 16
        f32x4 v = xp[768 + l];
        __builtin_nontemporal_store(v, op + 768 + l);
        s += (v.x + v.y) + (v.z + v.w);
    }

    #pragma unroll
    for (int off = 16; off > 0; off >>= 1)
        s += __shfl_xor(s, off, 32);
    if (l == 0)
        means[blockIdx.x * 8 + k] = s * (1.0f / HW);
}

// ---------------------------------------------------------------------------
// D2: redundant SE + zero-own-channels. 256 blocks x 256 threads = exactly
// 1 block/CU (no LDS contention; R12's 8 blocks/CU x rank-loop serialized
// on the LDS unit and cost ~60us). Each block owns 64 consecutive channels
// of batch b = bid>>3 (redundancy 8x, identical fp sequence -> bit-identical
// thr). Rank reads y2 as f32x4 (4x fewer LDS instructions).
// ---------------------------------------------------------------------------
__global__ __launch_bounds__(256) void se_zero_kernel(const float* __restrict__ means,
                                                      const float* __restrict__ W1,
                                                      const float* __restrict__ W2,
                                                      float* __restrict__ out) {
    const int tid = threadIdx.x;
    const int b = blockIdx.x >> 3;                 // 8 blocks per batch
    __shared__ float m[C];
    __shared__ float y1[HID];
    __shared__ f32x4 y2v[C / 4];                   // y2 as float4 for b128 reads
    __shared__ float thr;
    float* y2 = reinterpret_cast<float*>(y2v);

    m[tid]       = means[b * C + tid];
    m[tid + 256] = means[b * C + tid + 256];
    __syncthreads();

    {   // W1 dot: 8 lanes per hidden unit (h = tid>>3, l8 = tid&7)
        const int h = tid >> 3;
        const int l8 = tid & 7;
        const float* w = W1 + h * C;
        float acc = 0.f;
        for (int c = l8; c < C; c += 8) acc = fmaf(m[c], w[c], acc);
        #pragma unroll
        for (int off = 4; off > 0; off >>= 1) acc += __shfl_xor(acc, off, 8);
        if (l8 == 0) y1[h] = fmaxf(acc, 0.f);
    }
    __syncthreads();

    {   // W2 dot + sigmoid: channels tid and tid+256
        const float* w0 = W2 + tid * HID;
        const float* w1w = W2 + (tid + 256) * HID;
        float a0 = 0.f, a1 = 0.f;
        #pragma unroll
        for (int h = 0; h < HID; ++h) {
            a0 = fmaf(y1[h], w0[h], a0);
            a1 = fmaf(y1[h], w1w[h], a1);
        }
        y2[tid]       = 1.f / (1.f + expf(-a0));
        y2[tid + 256] = 1.f / (1.f + expf(-a1));
    }
    __syncthreads();

    {   // rank w/ index tie-break, vectorized y2 reads (b128 broadcast)
        const int c0 = tid, c1 = tid + 256;
        const float v0 = y2[c0], v1 = y2[c1];
        int r0 = 0, r1 = 0;
        #pragma unroll 8
        for (int j4 = 0; j4 < C / 4; ++j4) {
            f32x4 u = y2v[j4];
            const int jb = j4 * 4;
            #pragma unroll
            for (int e = 0; e < 4; ++e) {
                const float uu = u[e];
                const int j = jb + e;
                r0 += (uu < v0 || (uu == v0 && j < c0)) ? 1 : 0;
                r1 += (uu < v1 || (uu == v1 && j < c1)) ? 1 : 0;
            }
        }
        if (r0 == POS - 1) thr = v0;               // unique owner
        if (r1 == POS - 1) thr = v1;
    }
    __syncthreads();

    // ---- zero my 64 owned channels where y > thr (mask==0) ----
    const int cbase = (blockIdx.x & 7) * 64;       // channel offset in batch
    const float tval = thr;
    for (int s = 0; s < 64; ++s) {
        const int cc = cbase + s;
        if (y2[cc] > tval) {                       // wave-uniform branch
            f32x4* op = reinterpret_cast<f32x4*>(out) + ((size_t)b * C + cc) * HW4;
            const f32x4 z = {0.f, 0.f, 0.f, 0.f};
            for (int i = tid; i < HW4; i += 256)
                __builtin_nontemporal_store(z, op + i);
        }
    }
}

extern "C" void kernel_launch(void* const* d_in, const int* in_sizes, int n_in,
                              void* d_out, int out_size, void* d_ws, size_t ws_size,
                              hipStream_t stream) {
    const float* x  = (const float*)d_in[0];
    const float* W1 = (const float*)d_in[1];
    const float* W2 = (const float*)d_in[2];
    float* out = (float*)d_out;
    float* means = (float*)d_ws;                   // B*C floats = 64 KB

    copy_mean_kernel<<<2048, 256, 0, stream>>>(x, out, means);
    se_zero_kernel<<<256, 256, 0, stream>>>(means, W1, W2, out);
}